// Round 1
// baseline (2520.520 us; speedup 1.0000x reference)
//
#include <hip/hip_runtime.h>
#include <math.h>

#define D_MODEL 512
#define N_LAYERS 4
#define D_STATE 16
#define D_CONV 4
#define D_INNER 1024
#define DT_RANK 32
#define BATCH 2
#define SEQ 2048
#define NTOK (BATCH*SEQ)      // 4096 tokens
#define EPS 1e-5f

// chunked scan parameters
#define CHUNK 32
#define NCHUNK (SEQ/CHUNK)    // 64 chunks per batch

__device__ __forceinline__ float sigmoidf_(float x){ return 1.0f/(1.0f+__expf(-x)); }
__device__ __forceinline__ float softplusf_(float x){ return (x > 20.0f) ? x : log1pf(__expf(x)); }

// ---------------- RMSNorm: one block per token row (512 elems, 256 threads) ----------------
__global__ __launch_bounds__(256) void rmsnorm_k(const float* __restrict__ x,
                                                 const float* __restrict__ w,
                                                 float* __restrict__ out)
{
    int row = blockIdx.x;
    const float* xr = x + (size_t)row * D_MODEL;
    float v0 = xr[threadIdx.x];
    float v1 = xr[threadIdx.x + 256];
    float ss = v0*v0 + v1*v1;
    #pragma unroll
    for (int o = 32; o > 0; o >>= 1) ss += __shfl_down(ss, o, 64);
    __shared__ float red[4];
    int wid = threadIdx.x >> 6, lane = threadIdx.x & 63;
    if (lane == 0) red[wid] = ss;
    __syncthreads();
    float tot = red[0] + red[1] + red[2] + red[3];
    float sc = rsqrtf(tot / (float)D_MODEL + EPS);
    float* orow = out + (size_t)row * D_MODEL;
    orow[threadIdx.x]       = v0 * sc * w[threadIdx.x];
    orow[threadIdx.x + 256] = v1 * sc * w[threadIdx.x + 256];
}

// ---------------- Generic fp32 GEMM: C[M,N] = A[M,K(lda)] @ B[K,N], 128x128x16 tile ----------------
// EPI: 0 = plain store, 1 = softplus(acc + bias[col]), 2 = in-place residual (C += acc)
template<int EPI>
__global__ __launch_bounds__(256) void gemm_k(const float* __restrict__ A, int lda,
                                              const float* __restrict__ B,
                                              const float* __restrict__ bias,
                                              float* __restrict__ C,
                                              int M, int N, int K)
{
    __shared__ float sA[16][128];
    __shared__ float sB[16][128];
    int tid = threadIdx.x;
    int tx = tid & 15, ty = tid >> 4;
    int n0 = blockIdx.x * 128;
    int m0 = blockIdx.y * 128;
    float acc[8][8];
    #pragma unroll
    for (int i = 0; i < 8; i++)
        #pragma unroll
        for (int j = 0; j < 8; j++) acc[i][j] = 0.f;

    for (int k0 = 0; k0 < K; k0 += 16) {
        #pragma unroll
        for (int i = 0; i < 2; i++) {         // A tile: 128 rows x 16 k
            int r = tid + i * 256;
            int row = r >> 2, kq = (r & 3) * 4;
            const float4 av = *(const float4*)(A + (size_t)(m0 + row) * lda + k0 + kq);
            sA[kq+0][row] = av.x; sA[kq+1][row] = av.y;
            sA[kq+2][row] = av.z; sA[kq+3][row] = av.w;
        }
        #pragma unroll
        for (int i = 0; i < 2; i++) {         // B tile: 16 k x 128 cols
            int r = tid + i * 256;
            int kr = r >> 5, nq = (r & 31) * 4;
            float4 bv = make_float4(0.f, 0.f, 0.f, 0.f);
            if (n0 + nq < N) bv = *(const float4*)(B + (size_t)(k0 + kr) * N + n0 + nq);
            *(float4*)&sB[kr][nq] = bv;
        }
        __syncthreads();
        #pragma unroll
        for (int k = 0; k < 16; k++) {
            float4 a0 = *(const float4*)&sA[k][ty*8];
            float4 a1 = *(const float4*)&sA[k][ty*8+4];
            float4 b0 = *(const float4*)&sB[k][tx*8];
            float4 b1 = *(const float4*)&sB[k][tx*8+4];
            float a[8] = {a0.x,a0.y,a0.z,a0.w,a1.x,a1.y,a1.z,a1.w};
            float b[8] = {b0.x,b0.y,b0.z,b0.w,b1.x,b1.y,b1.z,b1.w};
            #pragma unroll
            for (int i = 0; i < 8; i++)
                #pragma unroll
                for (int j = 0; j < 8; j++)
                    acc[i][j] = fmaf(a[i], b[j], acc[i][j]);
        }
        __syncthreads();
    }

    #pragma unroll
    for (int i = 0; i < 8; i++) {
        int row = m0 + ty*8 + i;
        #pragma unroll
        for (int j = 0; j < 8; j++) {
            int col = n0 + tx*8 + j;
            if (col < N) {
                size_t off = (size_t)row * N + col;
                float v = acc[i][j];
                if (EPI == 1) v = softplusf_(v + bias[col]);
                else if (EPI == 2) v = v + C[off];
                C[off] = v;
            }
        }
    }
}

// ---------------- causal depthwise conv (k=4) + SiLU.  xi = xz[:, :D_INNER] ----------------
__global__ __launch_bounds__(256) void conv_silu_k(const float* __restrict__ xz,
                                                   const float* __restrict__ cw,
                                                   const float* __restrict__ cb,
                                                   float* __restrict__ xc)
{
    int idx = blockIdx.x * 256 + threadIdx.x;          // over NTOK*D_INNER
    int d = idx & (D_INNER - 1);
    int rowg = idx >> 10;                              // token index (b*SEQ+t)
    int t = rowg & (SEQ - 1);
    float acc = cb[d];
    float w0 = cw[d*4+0], w1 = cw[d*4+1], w2 = cw[d*4+2], w3 = cw[d*4+3];
    const float* base = xz + (size_t)rowg * (2*D_INNER) + d;
    float x3 = base[0];
    float x2 = (t >= 1) ? base[-(ptrdiff_t)(1*2*D_INNER)] : 0.f;
    float x1 = (t >= 2) ? base[-(ptrdiff_t)(2*2*D_INNER)] : 0.f;
    float x0 = (t >= 3) ? base[-(ptrdiff_t)(3*2*D_INNER)] : 0.f;
    acc = fmaf(w3,x3, fmaf(w2,x2, fmaf(w1,x1, fmaf(w0,x0, acc))));
    xc[idx] = acc * sigmoidf_(acc);
}

// ---------------- selective scan, 3-phase chunked ----------------
// phase A: per-chunk local scan (h0=0): y_local, final h, sum(delta)
__global__ __launch_bounds__(256) void scanA_k(const float* __restrict__ delta,
                                               const float* __restrict__ xc,
                                               const float* __restrict__ dbc,
                                               const float* __restrict__ A_log,
                                               float* __restrict__ ylocal,
                                               float* __restrict__ hbuf,
                                               float* __restrict__ dsumbuf)
{
    int blk = blockIdx.x;                    // BATCH * NCHUNK * 4
    int d = (blk & 3) * 256 + threadIdx.x;
    int c = (blk >> 2) & (NCHUNK - 1);
    int b = blk >> 8;                        // /(4*NCHUNK) = /256
    float A[16], h[16];
    #pragma unroll
    for (int s = 0; s < 16; s++) { A[s] = -__expf(A_log[d*16+s]); h[s] = 0.f; }
    float dsum = 0.f;
    int t0 = c * CHUNK;
    for (int t = 0; t < CHUNK; t++) {
        size_t row = (size_t)b * SEQ + t0 + t;
        float dl = delta[row * D_INNER + d];
        float x  = xc[row * D_INNER + d];
        const float* Bv = dbc + row * 64 + DT_RANK;
        const float* Cv = Bv + D_STATE;
        dsum += dl;
        float dx = dl * x;
        float y = 0.f;
        #pragma unroll
        for (int s = 0; s < 16; s++) {
            float dA = __expf(dl * A[s]);
            h[s] = fmaf(dA, h[s], dx * Bv[s]);
            y = fmaf(h[s], Cv[s], y);
        }
        ylocal[row * D_INNER + d] = y;
    }
    size_t hb = ((size_t)(b * NCHUNK + c) * D_INNER + d) * 16;
    #pragma unroll
    for (int s = 0; s < 16; s++) hbuf[hb + s] = h[s];
    dsumbuf[(size_t)(b * NCHUNK + c) * D_INNER + d] = dsum;
}

// phase B: sequential combine across chunks; emits h_in for every chunk
__global__ __launch_bounds__(256) void scanB_k(const float* __restrict__ hbuf,
                                               const float* __restrict__ dsumbuf,
                                               const float* __restrict__ A_log,
                                               float* __restrict__ hin)
{
    int g = blockIdx.x * 256 + threadIdx.x;  // 0 .. BATCH*D_INNER-1
    int d = g & (D_INNER - 1);
    int b = g >> 10;
    float A[16], h[16];
    #pragma unroll
    for (int s = 0; s < 16; s++) { A[s] = -__expf(A_log[d*16+s]); h[s] = 0.f; }
    for (int c = 0; c < NCHUNK; c++) {
        size_t base = ((size_t)(b * NCHUNK + c) * D_INNER + d) * 16;
        #pragma unroll
        for (int s = 0; s < 16; s++) hin[base + s] = h[s];
        float ds = dsumbuf[(size_t)(b * NCHUNK + c) * D_INNER + d];
        #pragma unroll
        for (int s = 0; s < 16; s++) h[s] = fmaf(__expf(ds * A[s]), h[s], hbuf[base + s]);
    }
}

// phase C: add incoming-state correction, + Dskip, then gate with silu(z). In-place on ylocal.
__global__ __launch_bounds__(256) void scanC_k(const float* __restrict__ delta,
                                               const float* __restrict__ xc,
                                               const float* __restrict__ dbc,
                                               const float* __restrict__ A_log,
                                               const float* __restrict__ Dskip,
                                               const float* __restrict__ xz,
                                               const float* __restrict__ hin,
                                               float* __restrict__ ymul)
{
    int blk = blockIdx.x;
    int d = (blk & 3) * 256 + threadIdx.x;
    int c = (blk >> 2) & (NCHUNK - 1);
    int b = blk >> 8;
    float A[16], hi[16];
    size_t hb = ((size_t)(b * NCHUNK + c) * D_INNER + d) * 16;
    #pragma unroll
    for (int s = 0; s < 16; s++) { A[s] = -__expf(A_log[d*16+s]); hi[s] = hin[hb + s]; }
    float Dv = Dskip[d];
    float cum = 0.f;
    int t0 = c * CHUNK;
    for (int t = 0; t < CHUNK; t++) {
        size_t row = (size_t)b * SEQ + t0 + t;
        float dl = delta[row * D_INNER + d];
        cum += dl;
        float x = xc[row * D_INNER + d];
        const float* Cv = dbc + row * 64 + DT_RANK + D_STATE;
        float yc = 0.f;
        #pragma unroll
        for (int s = 0; s < 16; s++)
            yc = fmaf(__expf(cum * A[s]) * hi[s], Cv[s], yc);
        float y = ymul[row * D_INNER + d] + yc + x * Dv;
        float z = xz[row * (2*D_INNER) + D_INNER + d];
        ymul[row * D_INNER + d] = y * z * sigmoidf_(z);
    }
}

// ---------------- head: logits[m] = dot(tokens[m,:], head_w) + head_b ----------------
__global__ __launch_bounds__(64) void head_k(const float* __restrict__ tokens,
                                             const float* __restrict__ hw,
                                             const float* __restrict__ hb,
                                             float* __restrict__ logits)
{
    int row = blockIdx.x;
    int lane = threadIdx.x;
    const float* tr = tokens + (size_t)row * D_MODEL;
    float s = 0.f;
    #pragma unroll
    for (int j = 0; j < 8; j++) s = fmaf(tr[lane + j*64], hw[lane + j*64], s);
    #pragma unroll
    for (int o = 32; o > 0; o >>= 1) s += __shfl_down(s, o, 64);
    if (lane == 0) logits[row] = s + hb[0];
}

extern "C" void kernel_launch(void* const* d_in, const int* in_sizes, int n_in,
                              void* d_out, int out_size, void* d_ws, size_t ws_size,
                              hipStream_t stream)
{
    const float* features = (const float*)d_in[0];
    const float* W_in   = (const float*)d_in[1];
    const float* conv_w = (const float*)d_in[2];
    const float* conv_b = (const float*)d_in[3];
    const float* W_x    = (const float*)d_in[4];
    const float* W_dt   = (const float*)d_in[5];
    const float* b_dt   = (const float*)d_in[6];
    const float* A_log  = (const float*)d_in[7];
    const float* Dskip  = (const float*)d_in[8];
    const float* W_out  = (const float*)d_in[9];
    const float* norm_w = (const float*)d_in[10];
    const float* norm_f = (const float*)d_in[11];
    const float* head_w = (const float*)d_in[12];
    const float* head_b = (const float*)d_in[13];

    float* out = (float*)d_out;
    float* logits = out;
    float* x = out + NTOK;            // tokens region doubles as the residual stream

    float* ws = (float*)d_ws;
    size_t o = 0;
    float* xz    = ws + o; o += (size_t)NTOK * 2 * D_INNER;            // 8.39M
    float* xc    = ws + o; o += (size_t)NTOK * D_INNER;                // 4.19M
    float* dbc   = ws + o; o += (size_t)NTOK * 64;                     // 0.26M
    float* delta = ws + o; o += (size_t)NTOK * D_INNER;                // 4.19M
    float* xn    = ws + o; float* ymul = xn; o += (size_t)NTOK * D_INNER; // aliased
    float* hbuf  = ws + o; o += (size_t)BATCH * NCHUNK * D_INNER * 16; // 2.10M
    float* dsumb = ws + o; o += (size_t)BATCH * NCHUNK * D_INNER;      // 0.13M
    float* hin   = ws + o; o += (size_t)BATCH * NCHUNK * D_INNER * 16; // 2.10M

    hipMemcpyAsync(x, features, sizeof(float) * (size_t)NTOK * D_MODEL,
                   hipMemcpyDeviceToDevice, stream);

    for (int l = 0; l < N_LAYERS; l++) {
        const float* Al = A_log + (size_t)l * D_INNER * D_STATE;

        rmsnorm_k<<<NTOK, 256, 0, stream>>>(x, norm_w + (size_t)l * D_MODEL, xn);

        dim3 g1(2*D_INNER/128, NTOK/128);
        gemm_k<0><<<g1, 256, 0, stream>>>(xn, D_MODEL,
            W_in + (size_t)l * D_MODEL * 2 * D_INNER, nullptr, xz,
            NTOK, 2*D_INNER, D_MODEL);

        conv_silu_k<<<NTOK*D_INNER/256, 256, 0, stream>>>(xz,
            conv_w + (size_t)l * D_INNER * D_CONV, conv_b + (size_t)l * D_INNER, xc);

        dim3 g2(1, NTOK/128);
        gemm_k<0><<<g2, 256, 0, stream>>>(xc, D_INNER,
            W_x + (size_t)l * D_INNER * 64, nullptr, dbc,
            NTOK, 64, D_INNER);

        dim3 g3(D_INNER/128, NTOK/128);
        gemm_k<1><<<g3, 256, 0, stream>>>(dbc, 64,
            W_dt + (size_t)l * DT_RANK * D_INNER, b_dt + (size_t)l * D_INNER, delta,
            NTOK, D_INNER, DT_RANK);

        int scan_blocks = BATCH * NCHUNK * (D_INNER/256);   // 512
        scanA_k<<<scan_blocks, 256, 0, stream>>>(delta, xc, dbc, Al, ymul, hbuf, dsumb);
        scanB_k<<<BATCH*D_INNER/256, 256, 0, stream>>>(hbuf, dsumb, Al, hin);
        scanC_k<<<scan_blocks, 256, 0, stream>>>(delta, xc, dbc, Al,
            Dskip + (size_t)l * D_INNER, xz, hin, ymul);

        dim3 g4(D_MODEL/128, NTOK/128);
        gemm_k<2><<<g4, 256, 0, stream>>>(ymul, D_INNER,
            W_out + (size_t)l * D_INNER * D_MODEL, nullptr, x,
            NTOK, D_MODEL, D_INNER);
    }

    rmsnorm_k<<<NTOK, 256, 0, stream>>>(x, norm_f, x);    // in-place -> tokens
    head_k<<<NTOK, 64, 0, stream>>>(x, head_w, head_b, logits);
}

// Round 2
// 815.126 us; speedup vs baseline: 3.0922x; 3.0922x over previous
//
#include <hip/hip_runtime.h>
#include <math.h>

#define D_MODEL 512
#define N_LAYERS 4
#define D_STATE 16
#define D_CONV 4
#define D_INNER 1024
#define DT_RANK 32
#define BATCH 2
#define SEQ 2048
#define NTOK (BATCH*SEQ)      // 4096 tokens
#define EPS 1e-5f

#define CHUNK 32
#define NCHUNK (SEQ/CHUNK)    // 64 chunks per batch

typedef __attribute__((ext_vector_type(8))) short s8v;
typedef __attribute__((ext_vector_type(4))) float f4v;

__device__ __forceinline__ float sigmoidf_(float x){ return 1.0f/(1.0f+__expf(-x)); }
__device__ __forceinline__ float softplusf_(float x){ return (x > 20.0f) ? x : log1pf(__expf(x)); }
__device__ __forceinline__ short f2bf(float x){
    unsigned u = __float_as_uint(x);
    unsigned r = (u + 0x7FFFu + ((u >> 16) & 1u)) >> 16;
    return (short)r;
}

// ---------------- transpose-cast: src fp32 [K][N] -> dst bf16 [N][K] ----------------
__global__ __launch_bounds__(256) void tcast_k(const float* __restrict__ src,
                                               short* __restrict__ dst, int K, int N)
{
    __shared__ float sm[32][33];
    int n0 = blockIdx.x * 32, k0 = blockIdx.y * 32;
    int tx = threadIdx.x & 31, ty = threadIdx.x >> 5;   // ty in [0,8)
    #pragma unroll
    for (int i = 0; i < 4; i++) {
        int k = ty + i * 8;
        sm[k][tx] = src[(size_t)(k0 + k) * N + n0 + tx];
    }
    __syncthreads();
    #pragma unroll
    for (int i = 0; i < 4; i++) {
        int n = ty + i * 8;
        dst[(size_t)(n0 + n) * K + k0 + tx] = f2bf(sm[tx][n]);
    }
}

// ---------------- RMSNorm: one block per token (512 elems). BF=bf16 output ----------------
template<bool BF>
__global__ __launch_bounds__(256) void rmsnorm_k(const float* __restrict__ x,
                                                 const float* __restrict__ w,
                                                 void* __restrict__ outp)
{
    int row = blockIdx.x;
    const float* xr = x + (size_t)row * D_MODEL;
    float v0 = xr[threadIdx.x];
    float v1 = xr[threadIdx.x + 256];
    float ss = v0*v0 + v1*v1;
    #pragma unroll
    for (int o = 32; o > 0; o >>= 1) ss += __shfl_down(ss, o, 64);
    __shared__ float red[4];
    int wid = threadIdx.x >> 6, lane = threadIdx.x & 63;
    if (lane == 0) red[wid] = ss;
    __syncthreads();
    float tot = red[0] + red[1] + red[2] + red[3];
    float sc = rsqrtf(tot / (float)D_MODEL + EPS);
    float o0 = v0 * sc * w[threadIdx.x];
    float o1 = v1 * sc * w[threadIdx.x + 256];
    if (BF) {
        short* orow = (short*)outp + (size_t)row * D_MODEL;
        orow[threadIdx.x]       = f2bf(o0);
        orow[threadIdx.x + 256] = f2bf(o1);
    } else {
        float* orow = (float*)outp + (size_t)row * D_MODEL;
        orow[threadIdx.x]       = o0;
        orow[threadIdx.x + 256] = o1;
    }
}

// ---------------- bf16 MFMA GEMM: C[M,N] = A[M,K] @ BT[N,K]^T ----------------
// A bf16 [M][lda]; BT bf16 [N][ldb] (i.e. B transposed); C fp32 [M][ldc].
// EPI: 0 plain store; 1 softplus(acc+bias[col]); 2 C += acc; 3 store fp32 C AND bf16 Cbf (ldc==N)
template<int BM, int BN, int EPI>
__global__ __launch_bounds__(256) void mgemm_k(const short* __restrict__ A, int lda,
                                               const short* __restrict__ BT, int ldb,
                                               const float* __restrict__ bias,
                                               float* __restrict__ C, int ldc,
                                               short* __restrict__ Cbf,
                                               int M, int N, int K)
{
    constexpr int WR = 2, WC = 2;
    constexpr int WM = BM / WR, WN = BN / WC;
    constexpr int TI = WM / 16, TJ = WN / 16;
    constexpr int LDK = 40;                    // 32 k + 8 pad (shorts): 2-way banks only
    constexpr int AITER = BM * 4 / 256;
    constexpr int BITER = BN * 4 / 256;
    __shared__ short sA[BM * LDK];
    __shared__ short sB[BN * LDK];
    int tid = threadIdx.x;
    int wave = tid >> 6, lane = tid & 63;
    int wm = (wave >> 1) * WM, wn = (wave & 1) * WN;
    int lh = lane & 15;                        // row/col within 16x16 tile
    int q  = lane >> 4;                        // k-quad (8 elems each)
    int m0 = blockIdx.y * BM, n0 = blockIdx.x * BN;

    f4v acc[TI][TJ];
    #pragma unroll
    for (int i = 0; i < TI; i++)
        #pragma unroll
        for (int j = 0; j < TJ; j++) { f4v z = {0.f,0.f,0.f,0.f}; acc[i][j] = z; }

    for (int k0 = 0; k0 < K; k0 += 32) {
        #pragma unroll
        for (int i = 0; i < AITER; i++) {
            int r = tid + i * 256;
            int row = r >> 2, kc = (r & 3) * 8;
            *(s8v*)&sA[row * LDK + kc] = *(const s8v*)&A[(size_t)(m0 + row) * lda + k0 + kc];
        }
        #pragma unroll
        for (int i = 0; i < BITER; i++) {
            int r = tid + i * 256;
            int row = r >> 2, kc = (r & 3) * 8;
            *(s8v*)&sB[row * LDK + kc] = *(const s8v*)&BT[(size_t)(n0 + row) * ldb + k0 + kc];
        }
        __syncthreads();
        s8v af[TI], bf[TJ];
        #pragma unroll
        for (int i = 0; i < TI; i++) af[i] = *(const s8v*)&sA[(wm + i*16 + lh) * LDK + q*8];
        #pragma unroll
        for (int j = 0; j < TJ; j++) bf[j] = *(const s8v*)&sB[(wn + j*16 + lh) * LDK + q*8];
        #pragma unroll
        for (int i = 0; i < TI; i++)
            #pragma unroll
            for (int j = 0; j < TJ; j++)
                acc[i][j] = __builtin_amdgcn_mfma_f32_16x16x32_bf16(af[i], bf[j], acc[i][j], 0, 0, 0);
        __syncthreads();
    }

    // C/D layout: col = lane&15, row = (lane>>4)*4 + reg   [verified m89/m91]
    #pragma unroll
    for (int i = 0; i < TI; i++) {
        #pragma unroll
        for (int j = 0; j < TJ; j++) {
            #pragma unroll
            for (int r = 0; r < 4; r++) {
                int row = m0 + wm + i*16 + q*4 + r;
                int col = n0 + wn + j*16 + lh;
                size_t off = (size_t)row * ldc + col;
                float v = acc[i][j][r];
                if (EPI == 1) v = softplusf_(v + bias[col]);
                else if (EPI == 2) v += C[off];
                C[off] = v;
                if (EPI == 3) Cbf[off] = f2bf(v);
            }
        }
    }
}

// ---------------- causal depthwise conv (k=4) + SiLU; dual fp32/bf16 output ----------------
__global__ __launch_bounds__(256) void conv_silu_k(const float* __restrict__ xz,
                                                   const float* __restrict__ cw,
                                                   const float* __restrict__ cb,
                                                   float* __restrict__ xc,
                                                   short* __restrict__ xc_bf)
{
    int idx = blockIdx.x * 256 + threadIdx.x;          // over NTOK*D_INNER
    int d = idx & (D_INNER - 1);
    int rowg = idx >> 10;
    int t = rowg & (SEQ - 1);
    float acc = cb[d];
    float w0 = cw[d*4+0], w1 = cw[d*4+1], w2 = cw[d*4+2], w3 = cw[d*4+3];
    const float* base = xz + (size_t)rowg * (2*D_INNER) + d;
    float x3 = base[0];
    float x2 = (t >= 1) ? base[-(ptrdiff_t)(1*2*D_INNER)] : 0.f;
    float x1 = (t >= 2) ? base[-(ptrdiff_t)(2*2*D_INNER)] : 0.f;
    float x0 = (t >= 3) ? base[-(ptrdiff_t)(3*2*D_INNER)] : 0.f;
    acc = fmaf(w3,x3, fmaf(w2,x2, fmaf(w1,x1, fmaf(w0,x0, acc))));
    float v = acc * sigmoidf_(acc);
    xc[idx] = v;
    xc_bf[idx] = f2bf(v);
}

// ---------------- selective scan, 3-phase chunked ----------------
// phase A: per-chunk local scan (h0=0). ylocal is written into xz[:, :D_INNER] (stride 2*D_INNER).
__global__ __launch_bounds__(256) void scanA_k(const float* __restrict__ delta,
                                               const float* __restrict__ xc,
                                               const float* __restrict__ dbc,
                                               const float* __restrict__ A_log,
                                               float* __restrict__ ylocal,   // stride 2*D_INNER
                                               float* __restrict__ hbuf,
                                               float* __restrict__ dsumbuf)
{
    int blk = blockIdx.x;                    // BATCH * NCHUNK * 4
    int d = (blk & 3) * 256 + threadIdx.x;
    int c = (blk >> 2) & (NCHUNK - 1);
    int b = blk >> 8;
    float A[16], h[16];
    #pragma unroll
    for (int s = 0; s < 16; s++) { A[s] = -__expf(A_log[d*16+s]); h[s] = 0.f; }
    float dsum = 0.f;
    int t0 = c * CHUNK;
    for (int t = 0; t < CHUNK; t++) {
        size_t row = (size_t)b * SEQ + t0 + t;
        float dl = delta[row * D_INNER + d];
        float x  = xc[row * D_INNER + d];
        const float* Bv = dbc + row * 64 + DT_RANK;
        const float* Cv = Bv + D_STATE;
        dsum += dl;
        float dx = dl * x;
        float y = 0.f;
        #pragma unroll
        for (int s = 0; s < 16; s++) {
            float dA = __expf(dl * A[s]);
            h[s] = fmaf(dA, h[s], dx * Bv[s]);
            y = fmaf(h[s], Cv[s], y);
        }
        ylocal[row * (2*D_INNER) + d] = y;
    }
    size_t hb = ((size_t)(b * NCHUNK + c) * D_INNER + d) * 16;
    #pragma unroll
    for (int s = 0; s < 16; s++) hbuf[hb + s] = h[s];
    dsumbuf[(size_t)(b * NCHUNK + c) * D_INNER + d] = dsum;
}

// phase B: sequential combine across chunks, one thread per (b,d,s)
__global__ __launch_bounds__(256) void scanB_k(const float* __restrict__ hbuf,
                                               const float* __restrict__ dsumbuf,
                                               const float* __restrict__ A_log,
                                               float* __restrict__ hin)
{
    int g = blockIdx.x * 256 + threadIdx.x;  // 0 .. BATCH*D_INNER*16-1
    int s = g & 15;
    int d = (g >> 4) & (D_INNER - 1);
    int b = g >> 14;
    float A = -__expf(A_log[d*16+s]);
    float h = 0.f;
    for (int c = 0; c < NCHUNK; c++) {
        size_t base = ((size_t)(b * NCHUNK + c) * D_INNER + d) * 16 + s;
        hin[base] = h;
        float ds = dsumbuf[(size_t)(b * NCHUNK + c) * D_INNER + d];
        h = fmaf(__expf(ds * A), h, hbuf[base]);
    }
}

// phase C: incoming-state correction + Dskip + silu(z) gate -> bf16 output for W_out GEMM
__global__ __launch_bounds__(256) void scanC_k(const float* __restrict__ delta,
                                               const float* __restrict__ xc,
                                               const float* __restrict__ dbc,
                                               const float* __restrict__ A_log,
                                               const float* __restrict__ Dskip,
                                               const float* __restrict__ xz,   // ylocal in lo half, z in hi half
                                               const float* __restrict__ hin,
                                               short* __restrict__ ymul_bf)
{
    int blk = blockIdx.x;
    int d = (blk & 3) * 256 + threadIdx.x;
    int c = (blk >> 2) & (NCHUNK - 1);
    int b = blk >> 8;
    float A[16], hi[16];
    size_t hb = ((size_t)(b * NCHUNK + c) * D_INNER + d) * 16;
    #pragma unroll
    for (int s = 0; s < 16; s++) { A[s] = -__expf(A_log[d*16+s]); hi[s] = hin[hb + s]; }
    float Dv = Dskip[d];
    float cum = 0.f;
    int t0 = c * CHUNK;
    for (int t = 0; t < CHUNK; t++) {
        size_t row = (size_t)b * SEQ + t0 + t;
        float dl = delta[row * D_INNER + d];
        cum += dl;
        float x = xc[row * D_INNER + d];
        const float* Cv = dbc + row * 64 + DT_RANK + D_STATE;
        float yc = 0.f;
        #pragma unroll
        for (int s = 0; s < 16; s++)
            yc = fmaf(__expf(cum * A[s]) * hi[s], Cv[s], yc);
        float y = xz[row * (2*D_INNER) + d] + yc + x * Dv;
        float z = xz[row * (2*D_INNER) + D_INNER + d];
        ymul_bf[row * D_INNER + d] = f2bf(y * z * sigmoidf_(z));
    }
}

// ---------------- head ----------------
__global__ __launch_bounds__(64) void head_k(const float* __restrict__ tokens,
                                             const float* __restrict__ hw,
                                             const float* __restrict__ hb,
                                             float* __restrict__ logits)
{
    int row = blockIdx.x;
    int lane = threadIdx.x;
    const float* tr = tokens + (size_t)row * D_MODEL;
    float s = 0.f;
    #pragma unroll
    for (int j = 0; j < 8; j++) s = fmaf(tr[lane + j*64], hw[lane + j*64], s);
    #pragma unroll
    for (int o = 32; o > 0; o >>= 1) s += __shfl_down(s, o, 64);
    if (lane == 0) logits[row] = s + hb[0];
}

extern "C" void kernel_launch(void* const* d_in, const int* in_sizes, int n_in,
                              void* d_out, int out_size, void* d_ws, size_t ws_size,
                              hipStream_t stream)
{
    const float* features = (const float*)d_in[0];
    const float* W_in   = (const float*)d_in[1];
    const float* conv_w = (const float*)d_in[2];
    const float* conv_b = (const float*)d_in[3];
    const float* W_x    = (const float*)d_in[4];
    const float* W_dt   = (const float*)d_in[5];
    const float* b_dt   = (const float*)d_in[6];
    const float* A_log  = (const float*)d_in[7];
    const float* Dskip  = (const float*)d_in[8];
    const float* W_out  = (const float*)d_in[9];
    const float* norm_w = (const float*)d_in[10];
    const float* norm_f = (const float*)d_in[11];
    const float* head_w = (const float*)d_in[12];
    const float* head_b = (const float*)d_in[13];

    float* out = (float*)d_out;
    float* logits = out;
    float* x = out + NTOK;            // tokens region doubles as the residual stream

    float* ws = (float*)d_ws;
    size_t o = 0;
    float* xz    = ws + o; o += (size_t)NTOK * 2 * D_INNER;            // also holds ylocal in lo half after conv
    float* xc    = ws + o; o += (size_t)NTOK * D_INNER;
    float* delta = ws + o; o += (size_t)NTOK * D_INNER;
    float* dbc   = ws + o; o += (size_t)NTOK * 64;
    float* hbuf  = ws + o; o += (size_t)BATCH * NCHUNK * D_INNER * 16;
    float* dsumb = ws + o; o += (size_t)BATCH * NCHUNK * D_INNER;
    float* hin   = ws + o; o += (size_t)BATCH * NCHUNK * D_INNER * 16;
    // shared bf16 activation buffer: xn_bf (2.1M) -> xc_bf (4.19M) -> ymul_bf (4.19M), sequential lifetimes
    short* bfA   = (short*)(ws + o); o += (size_t)NTOK * D_INNER / 2;
    short* dbc_bf= (short*)(ws + o); o += (size_t)NTOK * 64 / 2;
    short* WinT  = (short*)(ws + o); o += (size_t)2*D_INNER * D_MODEL / 2;  // [2048][512]
    short* WoutT = (short*)(ws + o); o += (size_t)D_MODEL * D_INNER / 2;    // [512][1024]
    short* WxT   = (short*)(ws + o); o += (size_t)64 * D_INNER / 2;         // [64][1024]
    short* WdtT  = (short*)(ws + o); o += (size_t)D_INNER * DT_RANK / 2;    // [1024][32]

    hipMemcpyAsync(x, features, sizeof(float) * (size_t)NTOK * D_MODEL,
                   hipMemcpyDeviceToDevice, stream);

    for (int l = 0; l < N_LAYERS; l++) {
        const float* Al = A_log + (size_t)l * D_INNER * D_STATE;

        // per-layer weight transpose-casts (bf16, [N][K])
        tcast_k<<<dim3(2*D_INNER/32, D_MODEL/32), 256, 0, stream>>>(
            W_in + (size_t)l * D_MODEL * 2*D_INNER, WinT, D_MODEL, 2*D_INNER);
        tcast_k<<<dim3(64/32, D_INNER/32), 256, 0, stream>>>(
            W_x + (size_t)l * D_INNER * 64, WxT, D_INNER, 64);
        tcast_k<<<dim3(D_INNER/32, DT_RANK/32), 256, 0, stream>>>(
            W_dt + (size_t)l * DT_RANK * D_INNER, WdtT, DT_RANK, D_INNER);
        tcast_k<<<dim3(D_MODEL/32, D_INNER/32), 256, 0, stream>>>(
            W_out + (size_t)l * D_INNER * D_MODEL, WoutT, D_INNER, D_MODEL);

        rmsnorm_k<true><<<NTOK, 256, 0, stream>>>(x, norm_w + (size_t)l * D_MODEL, bfA);

        // xz = xn @ W_in   [4096 x 2048], K=512
        mgemm_k<128,128,0><<<dim3(2*D_INNER/128, NTOK/128), 256, 0, stream>>>(
            bfA, D_MODEL, WinT, D_MODEL, nullptr, xz, 2*D_INNER, nullptr,
            NTOK, 2*D_INNER, D_MODEL);

        conv_silu_k<<<NTOK*D_INNER/256, 256, 0, stream>>>(xz,
            conv_w + (size_t)l * D_INNER * D_CONV, conv_b + (size_t)l * D_INNER,
            xc, bfA /* xc_bf */);

        // dbc = xc @ W_x   [4096 x 64], K=1024  (fp32 + bf16 dual store)
        mgemm_k<64,64,3><<<dim3(1, NTOK/64), 256, 0, stream>>>(
            bfA, D_INNER, WxT, D_INNER, nullptr, dbc, 64, dbc_bf,
            NTOK, 64, D_INNER);

        // delta = softplus(dt @ W_dt + b_dt)   [4096 x 1024], K=32
        mgemm_k<128,128,1><<<dim3(D_INNER/128, NTOK/128), 256, 0, stream>>>(
            dbc_bf, 64, WdtT, DT_RANK, b_dt + (size_t)l * D_INNER, delta, D_INNER, nullptr,
            NTOK, D_INNER, DT_RANK);

        int scan_blocks = BATCH * NCHUNK * (D_INNER/256);   // 512
        scanA_k<<<scan_blocks, 256, 0, stream>>>(delta, xc, dbc, Al, xz, hbuf, dsumb);
        scanB_k<<<BATCH*D_INNER*16/256, 256, 0, stream>>>(hbuf, dsumb, Al, hin);
        scanC_k<<<scan_blocks, 256, 0, stream>>>(delta, xc, dbc, Al,
            Dskip + (size_t)l * D_INNER, xz, hin, bfA /* ymul_bf */);

        // x += ymul @ W_out   [4096 x 512], K=1024
        mgemm_k<128,128,2><<<dim3(D_MODEL/128, NTOK/128), 256, 0, stream>>>(
            bfA, D_INNER, WoutT, D_INNER, nullptr, x, D_MODEL, nullptr,
            NTOK, D_MODEL, D_INNER);
    }

    rmsnorm_k<false><<<NTOK, 256, 0, stream>>>(x, norm_f, x);    // in-place -> tokens
    head_k<<<NTOK, 64, 0, stream>>>(x, head_w, head_b, logits);
}